// Round 8
// baseline (2286.309 us; speedup 1.0000x reference)
//
#include <hip/hip_runtime.h>

#define HID 64

// ALL float tensors are FLOAT32 per the reference (setup_inputs uses f32
// throughout; jax promotion keeps f32). Output = f32. Empirical rule from
// R0-R7: d_out writes landed only in the round using plain f32 stores (R3,
// whose NaN came from my bf16 misread of f32 inputs); ws proven usable
// through ~26MB (R3's tmp). This round: f32 everywhere, ws use = 26MB,
// 7 plain kernels / 18 launches, d_out written only via f32 stores/atomics.

// ---- 1. zero (deg accumulator) ----
__global__ void zero_kernel(float* __restrict__ p, int n) {
    int i = blockIdx.x * 256 + threadIdx.x, st = gridDim.x * 256;
    for (; i < n; i += st) p[i] = 0.0f;
}

// ---- 2. in-degree over dst ----
__global__ void deg_kernel(const int* __restrict__ dst, float* __restrict__ deg, int E) {
    int i = blockIdx.x * 256 + threadIdx.x, st = gridDim.x * 256;
    for (int e = i; e < E; e += st) atomicAdd(&deg[dst[e]], 1.0f);
}

// ---- 3. dinv = rsqrt(deg + 1)  (+1 = self loop) ----
__global__ void dinv_kernel(float* __restrict__ d, int N) {
    int i = blockIdx.x * 256 + threadIdx.x;
    if (i < N) d[i] = rsqrtf(d[i] + 1.0f);
}

// ---- 4. layer-0 GEMM: tmp[N,64] = x[N,128] @ W_in[128,64]  (all f32) ----
// K tiled in 2 chunks of 64 so LDS stays at 16KB + 2KB.
__global__ void gemm_in_kernel(const float* __restrict__ x, const float* __restrict__ W,
                               float* __restrict__ out, int N) {
    __shared__ float w_s[64 * HID];   // 16 KB
    __shared__ float h_s[4 * 128];    // 2 KB
    int tid = threadIdx.x;
    int n0 = blockIdx.x * 4;
    for (int i = tid; i < 4 * 128; i += 256) {
        int r = i >> 7, c = i & 127, nd = n0 + r;
        h_s[i] = (nd < N) ? x[(size_t)nd * 128 + c] : 0.0f;
    }
    int r = tid >> 6, col = tid & 63, nd = n0 + r;
    float acc = 0.0f;
    for (int kt = 0; kt < 2; ++kt) {
        __syncthreads();   // h_s ready (kt=0) / previous w_s reads done (kt=1)
        for (int i = tid; i < 64 * HID; i += 256)
            w_s[i] = W[(size_t)(kt * 64 + (i >> 6)) * HID + (i & 63)];
        __syncthreads();
        const float* hr = &h_s[r * 128 + kt * 64];
        #pragma unroll 8
        for (int k = 0; k < 64; ++k)
            acc = fmaf(hr[k], w_s[k * HID + col], acc);
    }
    if (nd < N) out[(size_t)nd * HID + col] = acc;
}

// ---- 5. hidden/out GEMM: tmp[N,64] = relu?(H[N,64]) @ W[64,64]  (all f32) ----
// H is read from d_out (previous layer's aggregate); relu applied on load.
__global__ void gemm_h_kernel(const float* __restrict__ H, const float* __restrict__ W,
                              float* __restrict__ out, int N, int do_relu) {
    __shared__ float w_s[HID * HID];  // 16 KB
    __shared__ float h_s[4 * HID];    // 1 KB
    int tid = threadIdx.x;
    for (int i = tid; i < HID * HID; i += 256) w_s[i] = W[i];
    int n0 = blockIdx.x * 4;
    {
        int r = tid >> 6, c = tid & 63, nd = n0 + r;
        float v = (nd < N) ? H[(size_t)nd * HID + c] : 0.0f;
        if (do_relu) v = fmaxf(v, 0.0f);
        h_s[tid] = v;
    }
    __syncthreads();
    int r = tid >> 6, col = tid & 63, nd = n0 + r;
    if (nd < N) {
        float acc = 0.0f;
        const float* hr = &h_s[r * HID];
        #pragma unroll 8
        for (int k = 0; k < HID; ++k)
            acc = fmaf(hr[k], w_s[k * HID + col], acc);
        out[(size_t)nd * HID + col] = acc;
    }
}

// ---- 6. init: ACC[d,c] = dinv[d]^2 * tmp[d,c] + bias[c]  (self-loop term) ----
// Fully overwrites ACC (= d_out), so no zeroing pass needed.
__global__ void init_kernel(const float* __restrict__ tmp, const float* __restrict__ dinv,
                            const float* __restrict__ bias, float* __restrict__ ACC, int NH) {
    int idx = blockIdx.x * 256 + threadIdx.x;
    if (idx < NH) {
        int d = idx >> 6, c = idx & 63;
        float di = dinv[d];
        float v = di * di * tmp[idx];
        if (bias != nullptr) v += bias[c];
        ACC[idx] = v;
    }
}

// ---- 7. edge aggregation: ACC[dst,c] += dinv[src]*dinv[dst] * tmp[src,c] ----
// 64 lanes per edge: coalesced 256B gather + coalesced f32 atomics.
__global__ void agg_kernel(const int* __restrict__ src, const int* __restrict__ dst,
                           const float* __restrict__ dinv, const float* __restrict__ tmp,
                           float* __restrict__ ACC, int E) {
    int tid = threadIdx.x;
    int e = blockIdx.x * 4 + (tid >> 6);
    int c = tid & 63;
    if (e < E) {
        int s = src[e], d = dst[e];
        float nrm = dinv[s] * dinv[d];
        atomicAdd(&ACC[(size_t)d * HID + c], nrm * tmp[(size_t)s * HID + c]);
    }
}

extern "C" void kernel_launch(void* const* d_in, const int* in_sizes, int n_in,
                              void* d_out, int out_size, void* d_ws, size_t ws_size,
                              hipStream_t stream) {
    const float* x     = (const float*)d_in[0];   // f32 [N,128]
    const int*   ei    = (const int*)d_in[1];     // int32 [2,E]
    const float* W_in  = (const float*)d_in[2];   // f32 [128,64]
    const float* b_in  = (const float*)d_in[3];   // f32 [64]
    const float* W_h   = (const float*)d_in[4];   // f32 [3,64,64]
    const float* b_h   = (const float*)d_in[5];   // f32 [3,64]
    const float* W_out = (const float*)d_in[6];   // f32 [64,64]

    const int K0 = in_sizes[2] / HID;   // 128
    const int N  = in_sizes[0] / K0;    // 100000
    const int E  = in_sizes[1] / 2;     // 1600000
    const int* srcp = ei;
    const int* dstp = ei + E;

    const int NH = N * HID;
    float* ACC  = (float*)d_out;                      // f32 [N,64] = exactly d_out
    float* dinv = (float*)d_ws;                       // 0.4 MB
    float* tmp  = dinv + (((size_t)N + 255) & ~(size_t)255);  // 25.6 MB (ws total 26MB, R3-proven)

    const int ggrid = (N + 3) / 4;
    const int agrid = (E + 3) / 4;
    const int ngrid = (NH + 255) / 256;

    // ---- normalization (3 launches) ----
    zero_kernel<<<512, 256, 0, stream>>>(dinv, N);
    deg_kernel<<<2048, 256, 0, stream>>>(dstp, dinv, E);
    dinv_kernel<<<(N + 255) / 256, 256, 0, stream>>>(dinv, N);

    // ---- conv_in: +bias, no relu yet (relu'd on load of next gemm? no — conv_in has no relu) ----
    gemm_in_kernel<<<ggrid, 256, 0, stream>>>(x, W_in, tmp, N);
    init_kernel<<<ngrid, 256, 0, stream>>>(tmp, dinv, b_in, ACC, NH);
    agg_kernel<<<agrid, 256, 0, stream>>>(srcp, dstp, dinv, tmp, ACC, E);

    // ---- hidden convs 1..3: relu applied on LOAD of convs 2,3 (and out conv) ----
    for (int l = 0; l < 3; ++l) {
        gemm_h_kernel<<<ggrid, 256, 0, stream>>>(ACC, W_h + (size_t)l * HID * HID, tmp, N, l > 0 ? 1 : 0);
        init_kernel<<<ngrid, 256, 0, stream>>>(tmp, dinv, b_h + (size_t)l * HID, ACC, NH);
        agg_kernel<<<agrid, 256, 0, stream>>>(srcp, dstp, dinv, tmp, ACC, E);
    }

    // ---- out conv: relu'd input, no bias; final aggregate lands in d_out (f32) ----
    gemm_h_kernel<<<ggrid, 256, 0, stream>>>(ACC, W_out, tmp, N, 1);
    init_kernel<<<ngrid, 256, 0, stream>>>(tmp, dinv, nullptr, ACC, NH);
    agg_kernel<<<agrid, 256, 0, stream>>>(srcp, dstp, dinv, tmp, ACC, E);
}

// Round 9
// 1031.960 us; speedup vs baseline: 2.2155x; 2.2155x over previous
//
#include <hip/hip_runtime.h>

#define HID 64

// R8 passed (2286us): agg atomics = 76% of runtime, WRITE_SIZE 400MB/layer
// (every 256B atomic RMW writes through to HBM). R9: CSR two-phase aggregation
// - build dst-sorted edge list once (deg -> scan -> scatter), then one wave
//   per dst node accumulates in registers and stores once (WRITE 400->26MB).
// - init (self-loop) + bias + relu folded into agg epilogue.

// ---- zero ints ----
__global__ void zero_i(int* __restrict__ p, int n) {
    int i = blockIdx.x * 256 + threadIdx.x, st = gridDim.x * 256;
    for (; i < n; i += st) p[i] = 0;
}

// ---- int in-degree over dst ----
__global__ void deg_i(const int* __restrict__ dst, int* __restrict__ deg, int E) {
    int i = blockIdx.x * 256 + threadIdx.x, st = gridDim.x * 256;
    for (int e = i; e < E; e += st) atomicAdd(&deg[dst[e]], 1);
}

// ---- dinv = rsqrt(deg+1) ----
__global__ void dinv_k(const int* __restrict__ deg, float* __restrict__ dinv, int N) {
    int i = blockIdx.x * 256 + threadIdx.x;
    if (i < N) dinv[i] = rsqrtf((float)deg[i] + 1.0f);
}

// ---- scan stage 1: per-block (1024 elems) exclusive scan + block sums ----
__global__ void scan1(const int* __restrict__ in, int* __restrict__ out,
                      int* __restrict__ bsum, int n) {
    __shared__ int s[256];
    int t = threadIdx.x, base = blockIdx.x * 1024 + t * 4;
    int v0 = 0, v1 = 0, v2 = 0, v3 = 0;
    if (base + 0 < n) v0 = in[base + 0];
    if (base + 1 < n) v1 = in[base + 1];
    if (base + 2 < n) v2 = in[base + 2];
    if (base + 3 < n) v3 = in[base + 3];
    int sum = v0 + v1 + v2 + v3;
    s[t] = sum; __syncthreads();
    for (int off = 1; off < 256; off <<= 1) {
        int x = (t >= off) ? s[t - off] : 0;
        __syncthreads(); s[t] += x; __syncthreads();
    }
    if (t == 255) bsum[blockIdx.x] = s[255];
    int run = s[t] - sum;
    if (base + 0 < n) out[base + 0] = run; run += v0;
    if (base + 1 < n) out[base + 1] = run; run += v1;
    if (base + 2 < n) out[base + 2] = run; run += v2;
    if (base + 3 < n) out[base + 3] = run;
}

// ---- scan stage 2: single-block exclusive scan of block sums (nb<=1024) ----
__global__ void scan2(int* __restrict__ bsum, int nb) {
    __shared__ int s[256];
    int t = threadIdx.x, base = t * 4;
    int v0 = 0, v1 = 0, v2 = 0, v3 = 0;
    if (base + 0 < nb) v0 = bsum[base + 0];
    if (base + 1 < nb) v1 = bsum[base + 1];
    if (base + 2 < nb) v2 = bsum[base + 2];
    if (base + 3 < nb) v3 = bsum[base + 3];
    int sum = v0 + v1 + v2 + v3;
    s[t] = sum; __syncthreads();
    for (int off = 1; off < 256; off <<= 1) {
        int x = (t >= off) ? s[t - off] : 0;
        __syncthreads(); s[t] += x; __syncthreads();
    }
    int run = s[t] - sum;
    if (base + 0 < nb) bsum[base + 0] = run; run += v0;
    if (base + 1 < nb) bsum[base + 1] = run; run += v1;
    if (base + 2 < nb) bsum[base + 2] = run; run += v2;
    if (base + 3 < nb) bsum[base + 3] = run;
}

// ---- scan stage 3: add block offsets; set row_ptr[N]=E ----
__global__ void scan3(int* __restrict__ out, const int* __restrict__ bsum,
                      int n, int N, int E) {
    int i = blockIdx.x * 256 + threadIdx.x;
    if (i < n) out[i] += bsum[i >> 10];
    if (i == 0) out[N] = E;
}

// ---- scatter edges into CSR buckets; enorm = dinv[s]*dinv[d] ----
__global__ void scatter_k(const int* __restrict__ src, const int* __restrict__ dst,
                          const int* __restrict__ rp, int* __restrict__ cursor,
                          const float* __restrict__ dinv,
                          int* __restrict__ esrc, float* __restrict__ enorm, int E) {
    int i = blockIdx.x * 256 + threadIdx.x, st = gridDim.x * 256;
    for (int e = i; e < E; e += st) {
        int s = src[e], d = dst[e];
        int pos = rp[d] + atomicAdd(&cursor[d], 1);
        esrc[pos] = s;
        enorm[pos] = dinv[s] * dinv[d];
    }
}

// ---- layer-0 GEMM: tmp[N,64] = x[N,128] @ W_in[128,64] ----
__global__ void gemm_in_kernel(const float* __restrict__ x, const float* __restrict__ W,
                               float* __restrict__ out, int N) {
    __shared__ float w_s[64 * HID];   // 16 KB
    __shared__ float h_s[4 * 128];    // 2 KB
    int tid = threadIdx.x;
    int n0 = blockIdx.x * 4;
    for (int i = tid; i < 4 * 128; i += 256) {
        int r = i >> 7, c = i & 127, nd = n0 + r;
        h_s[i] = (nd < N) ? x[(size_t)nd * 128 + c] : 0.0f;
    }
    int r = tid >> 6, col = tid & 63, nd = n0 + r;
    float acc = 0.0f;
    for (int kt = 0; kt < 2; ++kt) {
        __syncthreads();
        for (int i = tid; i < 64 * HID; i += 256)
            w_s[i] = W[(size_t)(kt * 64 + (i >> 6)) * HID + (i & 63)];
        __syncthreads();
        const float* hr = &h_s[r * 128 + kt * 64];
        #pragma unroll 8
        for (int k = 0; k < 64; ++k)
            acc = fmaf(hr[k], w_s[k * HID + col], acc);
    }
    if (nd < N) out[(size_t)nd * HID + col] = acc;
}

// ---- hidden/out GEMM: tmp[N,64] = H[N,64] @ W[64,64] (relu pre-applied) ----
__global__ void gemm_h_kernel(const float* __restrict__ H, const float* __restrict__ W,
                              float* __restrict__ out, int N) {
    __shared__ float w_s[HID * HID];  // 16 KB
    __shared__ float h_s[4 * HID];    // 1 KB
    int tid = threadIdx.x;
    for (int i = tid; i < HID * HID; i += 256) w_s[i] = W[i];
    int n0 = blockIdx.x * 4;
    {
        int r = tid >> 6, c = tid & 63, nd = n0 + r;
        h_s[tid] = (nd < N) ? H[(size_t)nd * HID + c] : 0.0f;
    }
    __syncthreads();
    int r = tid >> 6, col = tid & 63, nd = n0 + r;
    if (nd < N) {
        float acc = 0.0f;
        const float* hr = &h_s[r * HID];
        #pragma unroll 8
        for (int k = 0; k < HID; ++k)
            acc = fmaf(hr[k], w_s[k * HID + col], acc);
        out[(size_t)nd * HID + col] = acc;
    }
}

// ---- CSR aggregation, one wave per dst node; init+bias+relu fused ----
// out[d,c] = relu?( dinv[d]^2*tmp[d,c] + sum_j enorm[j]*tmp[esrc[j],c] + bias[c] )
__global__ void agg_csr(const float* __restrict__ tmp, const int* __restrict__ rp,
                        const int* __restrict__ esrc, const float* __restrict__ enorm,
                        const float* __restrict__ dinv, const float* __restrict__ bias,
                        float* __restrict__ out, int N, int do_relu) {
    int d = blockIdx.x * 4 + (threadIdx.x >> 6);
    int col = threadIdx.x & 63;
    if (d >= N) return;
    float di = dinv[d];
    float acc = di * di * tmp[(size_t)d * HID + col];
    int j0 = rp[d], j1 = rp[d + 1];
    int j = j0;
    // 2-deep software pipeline on the (uniform) edge index stream
    for (; j + 1 < j1; j += 2) {
        int s0 = esrc[j], s1 = esrc[j + 1];
        float n0 = enorm[j], n1 = enorm[j + 1];
        float t0 = tmp[(size_t)s0 * HID + col];
        float t1 = tmp[(size_t)s1 * HID + col];
        acc = fmaf(n0, t0, acc);
        acc = fmaf(n1, t1, acc);
    }
    if (j < j1) {
        int s0 = esrc[j];
        acc = fmaf(enorm[j], tmp[(size_t)s0 * HID + col], acc);
    }
    if (bias != nullptr) acc += bias[col];
    if (do_relu) acc = fmaxf(acc, 0.0f);
    out[(size_t)d * HID + col] = acc;
}

extern "C" void kernel_launch(void* const* d_in, const int* in_sizes, int n_in,
                              void* d_out, int out_size, void* d_ws, size_t ws_size,
                              hipStream_t stream) {
    const float* x     = (const float*)d_in[0];   // f32 [N,128]
    const int*   ei    = (const int*)d_in[1];     // int32 [2,E]
    const float* W_in  = (const float*)d_in[2];   // f32 [128,64]
    const float* b_in  = (const float*)d_in[3];   // f32 [64]
    const float* W_h   = (const float*)d_in[4];   // f32 [3,64,64]
    const float* b_h   = (const float*)d_in[5];   // f32 [3,64]
    const float* W_out = (const float*)d_in[6];   // f32 [64,64]

    const int K0 = in_sizes[2] / HID;   // 128
    const int N  = in_sizes[0] / K0;    // 100000
    const int E  = in_sizes[1] / 2;     // 1600000
    const int* srcp = ei;
    const int* dstp = ei + E;

    const int NH = N * HID;
    const size_t Npad = ((size_t)N + 255) & ~(size_t)255;

    float* ACC  = (float*)d_out;          // H buffer / final output, f32 [N,64]
    float* dinv = (float*)d_ws;           // Npad f32
    float* tmp  = dinv + Npad;            // NH f32   (ws so far: 26.0 MB, R8-proven)

    // CSR scratch: degi/cursor (2*Npad), row_ptr (Npad+256), bsum (1024),
    // esrc (E), enorm (E)  -> ~14.1 MB
    size_t csr_elems = 2 * Npad + (Npad + 256) + 1024 + 2 * (size_t)E;
    size_t ws_need_big = (Npad + (size_t)NH + csr_elems) * 4;
    int* csr_base;
    if (ws_size >= ws_need_big) {
        csr_base = (int*)(tmp + NH);              // everything in d_ws
    } else {
        csr_base = (int*)d_in[0];                 // x buffer after gemm_in consumes it
    }
    int*   degi   = csr_base;
    int*   cursor = degi + Npad;
    int*   rp     = cursor + Npad;                // N+1 used
    int*   bsum   = rp + Npad + 256;
    int*   esrc   = bsum + 1024;
    float* enorm  = (float*)(esrc + E);

    const int ggrid = (N + 3) / 4;
    const int nb    = (N + 1023) / 1024;

    // ---- layer-0 transform first (frees x for CSR scratch if needed) ----
    gemm_in_kernel<<<ggrid, 256, 0, stream>>>(x, W_in, tmp, N);

    // ---- degree + norm ----
    zero_i<<<256, 256, 0, stream>>>(degi, (int)(2 * Npad));     // degi + cursor
    deg_i<<<2048, 256, 0, stream>>>(dstp, degi, E);
    dinv_k<<<(N + 255) / 256, 256, 0, stream>>>(degi, dinv, N);

    // ---- CSR build: exclusive scan of degi -> rp; scatter edges ----
    scan1<<<nb, 256, 0, stream>>>(degi, rp, bsum, N);
    scan2<<<1, 256, 0, stream>>>(bsum, nb);
    scan3<<<(N + 255) / 256, 256, 0, stream>>>(rp, bsum, N, N, E);
    scatter_k<<<2048, 256, 0, stream>>>(srcp, dstp, rp, cursor, dinv, esrc, enorm, E);

    // ---- 5 GCN convs ----
    // layer 0: tmp ready; +b_in, no relu
    agg_csr<<<ggrid, 256, 0, stream>>>(tmp, rp, esrc, enorm, dinv, b_in, ACC, N, 0);
    // hidden 1..3: +b_h[l], relu
    for (int l = 0; l < 3; ++l) {
        gemm_h_kernel<<<ggrid, 256, 0, stream>>>(ACC, W_h + (size_t)l * HID * HID, tmp, N);
        agg_csr<<<ggrid, 256, 0, stream>>>(tmp, rp, esrc, enorm, dinv, b_h + (size_t)l * HID, ACC, N, 1);
    }
    // out: no bias, no relu
    gemm_h_kernel<<<ggrid, 256, 0, stream>>>(ACC, W_out, tmp, N);
    agg_csr<<<ggrid, 256, 0, stream>>>(tmp, rp, esrc, enorm, dinv, nullptr, ACC, N, 0);
}

// Round 10
// 781.188 us; speedup vs baseline: 2.9267x; 1.3210x over previous
//
#include <hip/hip_runtime.h>

#define HID 64

// R9: 1032us. gemm_in=110us was LDS-issue bound (2 ds_read_b32 per fma).
// R10: (1) register-tiled GEMM: 4x4 tile/thread, 4 b32 + 1 b128 LDS reads
// per 16 fma, k-chunked at 64 (32.6KB LDS, padded h layout, conflict-free).
// (2) CSR payload packed int2(src, dinv[src]) - one 8B random store in
// scatter (was 2x4B), dinv[d] factored out of the agg edge-sum.

// ---- zero ints ----
__global__ void zero_i(int* __restrict__ p, int n) {
    int i = blockIdx.x * 256 + threadIdx.x, st = gridDim.x * 256;
    for (; i < n; i += st) p[i] = 0;
}

// ---- int in-degree over dst ----
__global__ void deg_i(const int* __restrict__ dst, int* __restrict__ deg, int E) {
    int i = blockIdx.x * 256 + threadIdx.x, st = gridDim.x * 256;
    for (int e = i; e < E; e += st) atomicAdd(&deg[dst[e]], 1);
}

// ---- dinv = rsqrt(deg+1) ----
__global__ void dinv_k(const int* __restrict__ deg, float* __restrict__ dinv, int N) {
    int i = blockIdx.x * 256 + threadIdx.x;
    if (i < N) dinv[i] = rsqrtf((float)deg[i] + 1.0f);
}

// ---- scan stage 1: per-block (1024 elems) exclusive scan + block sums ----
__global__ void scan1(const int* __restrict__ in, int* __restrict__ out,
                      int* __restrict__ bsum, int n) {
    __shared__ int s[256];
    int t = threadIdx.x, base = blockIdx.x * 1024 + t * 4;
    int v0 = 0, v1 = 0, v2 = 0, v3 = 0;
    if (base + 0 < n) v0 = in[base + 0];
    if (base + 1 < n) v1 = in[base + 1];
    if (base + 2 < n) v2 = in[base + 2];
    if (base + 3 < n) v3 = in[base + 3];
    int sum = v0 + v1 + v2 + v3;
    s[t] = sum; __syncthreads();
    for (int off = 1; off < 256; off <<= 1) {
        int x = (t >= off) ? s[t - off] : 0;
        __syncthreads(); s[t] += x; __syncthreads();
    }
    if (t == 255) bsum[blockIdx.x] = s[255];
    int run = s[t] - sum;
    if (base + 0 < n) out[base + 0] = run; run += v0;
    if (base + 1 < n) out[base + 1] = run; run += v1;
    if (base + 2 < n) out[base + 2] = run; run += v2;
    if (base + 3 < n) out[base + 3] = run;
}

// ---- scan stage 2: single-block scan of block sums (nb<=1024) ----
__global__ void scan2(int* __restrict__ bsum, int nb) {
    __shared__ int s[256];
    int t = threadIdx.x, base = t * 4;
    int v0 = 0, v1 = 0, v2 = 0, v3 = 0;
    if (base + 0 < nb) v0 = bsum[base + 0];
    if (base + 1 < nb) v1 = bsum[base + 1];
    if (base + 2 < nb) v2 = bsum[base + 2];
    if (base + 3 < nb) v3 = bsum[base + 3];
    int sum = v0 + v1 + v2 + v3;
    s[t] = sum; __syncthreads();
    for (int off = 1; off < 256; off <<= 1) {
        int x = (t >= off) ? s[t - off] : 0;
        __syncthreads(); s[t] += x; __syncthreads();
    }
    int run = s[t] - sum;
    if (base + 0 < nb) bsum[base + 0] = run; run += v0;
    if (base + 1 < nb) bsum[base + 1] = run; run += v1;
    if (base + 2 < nb) bsum[base + 2] = run; run += v2;
    if (base + 3 < nb) bsum[base + 3] = run;
}

// ---- scan stage 3: add block offsets; set rp[N]=E ----
__global__ void scan3(int* __restrict__ out, const int* __restrict__ bsum,
                      int n, int N, int E) {
    int i = blockIdx.x * 256 + threadIdx.x;
    if (i < n) out[i] += bsum[i >> 10];
    if (i == 0) out[N] = E;
}

// ---- scatter edges: epay[pos] = (src, dinv[src]) packed 8B ----
__global__ void scatter_k(const int* __restrict__ src, const int* __restrict__ dst,
                          const int* __restrict__ rp, int* __restrict__ cursor,
                          const float* __restrict__ dinv, int2* __restrict__ epay, int E) {
    int i = blockIdx.x * 256 + threadIdx.x, st = gridDim.x * 256;
    for (int e = i; e < E; e += st) {
        int s = src[e], d = dst[e];
        int pos = rp[d] + atomicAdd(&cursor[d], 1);
        epay[pos] = make_int2(s, __float_as_int(dinv[s]));
    }
}

// ---- register-tiled GEMM: out[N,64] = H[N,K] @ W[K,64], K in {64,128} ----
// block = 256 thr, 64 rows x 64 cols tile; thread = 4 rows x 4 cols.
// per k: 4x ds_read_b32 (h, broadcast) + 1x ds_read_b128 (w) -> 16 fma.
__global__ void gemm_tile(const float* __restrict__ H, const float* __restrict__ W,
                          float* __restrict__ out, int N, int K) {
    __shared__ float h_s[64 * 65];   // [row][k] chunk, +1 pad: conflict-free
    __shared__ float w_s[64 * 64];   // [k][col] chunk
    int tid  = threadIdx.x;
    int col4 = tid & 15;             // 16 col groups (4 cols each)
    int rq   = (tid >> 4) & 3;
    int wv   = tid >> 6;
    int row0 = wv * 16 + rq * 4;     // this thread's 4 rows (tile-local)
    int n0   = blockIdx.x * 64;
    float4 acc0 = {0,0,0,0}, acc1 = {0,0,0,0}, acc2 = {0,0,0,0}, acc3 = {0,0,0,0};
    int nchunk = K >> 6;
    for (int kc = 0; kc < nchunk; ++kc) {
        __syncthreads();
        for (int i = tid; i < 64 * 64; i += 256) {        // h chunk, coalesced
            int r = i >> 6, k = i & 63;
            int nd = n0 + r;
            h_s[r * 65 + k] = (nd < N) ? H[(size_t)nd * K + kc * 64 + k] : 0.0f;
        }
        for (int i = tid; i < 64 * 64; i += 256) {        // w chunk [k][col]
            int k = i >> 6, c = i & 63;
            w_s[i] = W[(size_t)(kc * 64 + k) * HID + c];
        }
        __syncthreads();
        #pragma unroll 8
        for (int k = 0; k < 64; ++k) {
            float4 w = *(const float4*)&w_s[k * 64 + col4 * 4];
            float h0 = h_s[(row0 + 0) * 65 + k];
            float h1 = h_s[(row0 + 1) * 65 + k];
            float h2 = h_s[(row0 + 2) * 65 + k];
            float h3 = h_s[(row0 + 3) * 65 + k];
            acc0.x = fmaf(h0, w.x, acc0.x); acc0.y = fmaf(h0, w.y, acc0.y);
            acc0.z = fmaf(h0, w.z, acc0.z); acc0.w = fmaf(h0, w.w, acc0.w);
            acc1.x = fmaf(h1, w.x, acc1.x); acc1.y = fmaf(h1, w.y, acc1.y);
            acc1.z = fmaf(h1, w.z, acc1.z); acc1.w = fmaf(h1, w.w, acc1.w);
            acc2.x = fmaf(h2, w.x, acc2.x); acc2.y = fmaf(h2, w.y, acc2.y);
            acc2.z = fmaf(h2, w.z, acc2.z); acc2.w = fmaf(h2, w.w, acc2.w);
            acc3.x = fmaf(h3, w.x, acc3.x); acc3.y = fmaf(h3, w.y, acc3.y);
            acc3.z = fmaf(h3, w.z, acc3.z); acc3.w = fmaf(h3, w.w, acc3.w);
        }
    }
    int nd0 = n0 + row0;
    if (nd0 + 0 < N) *(float4*)&out[(size_t)(nd0 + 0) * HID + col4 * 4] = acc0;
    if (nd0 + 1 < N) *(float4*)&out[(size_t)(nd0 + 1) * HID + col4 * 4] = acc1;
    if (nd0 + 2 < N) *(float4*)&out[(size_t)(nd0 + 2) * HID + col4 * 4] = acc2;
    if (nd0 + 3 < N) *(float4*)&out[(size_t)(nd0 + 3) * HID + col4 * 4] = acc3;
}

// ---- CSR aggregation, wave per dst node; self-loop+bias+relu fused ----
// out[d] = relu?( di^2*tmp[d] + di*sum_j dinv[s_j]*tmp[s_j] + bias )
__global__ void agg_csr(const float* __restrict__ tmp, const int* __restrict__ rp,
                        const int2* __restrict__ epay, const float* __restrict__ dinv,
                        const float* __restrict__ bias, float* __restrict__ out,
                        int N, int do_relu) {
    int d = blockIdx.x * 4 + (threadIdx.x >> 6);
    int col = threadIdx.x & 63;
    if (d >= N) return;
    float di = dinv[d];
    float self = tmp[(size_t)d * HID + col];
    int j0 = rp[d], j1 = rp[d + 1];
    float accE = 0.0f;
    int j = j0;
    for (; j + 3 < j1; j += 4) {                 // 4-deep: 4 gathers in flight
        int2 p0 = epay[j], p1 = epay[j + 1], p2 = epay[j + 2], p3 = epay[j + 3];
        float t0 = tmp[(size_t)p0.x * HID + col];
        float t1 = tmp[(size_t)p1.x * HID + col];
        float t2 = tmp[(size_t)p2.x * HID + col];
        float t3 = tmp[(size_t)p3.x * HID + col];
        accE = fmaf(__int_as_float(p0.y), t0, accE);
        accE = fmaf(__int_as_float(p1.y), t1, accE);
        accE = fmaf(__int_as_float(p2.y), t2, accE);
        accE = fmaf(__int_as_float(p3.y), t3, accE);
    }
    for (; j < j1; ++j) {
        int2 p = epay[j];
        accE = fmaf(__int_as_float(p.y), tmp[(size_t)p.x * HID + col], accE);
    }
    float v = fmaf(di, accE, di * di * self);
    if (bias != nullptr) v += bias[col];
    if (do_relu) v = fmaxf(v, 0.0f);
    out[(size_t)d * HID + col] = v;
}

extern "C" void kernel_launch(void* const* d_in, const int* in_sizes, int n_in,
                              void* d_out, int out_size, void* d_ws, size_t ws_size,
                              hipStream_t stream) {
    const float* x     = (const float*)d_in[0];   // f32 [N,128]
    const int*   ei    = (const int*)d_in[1];     // int32 [2,E]
    const float* W_in  = (const float*)d_in[2];   // f32 [128,64]
    const float* b_in  = (const float*)d_in[3];   // f32 [64]
    const float* W_h   = (const float*)d_in[4];   // f32 [3,64,64]
    const float* b_h   = (const float*)d_in[5];   // f32 [3,64]
    const float* W_out = (const float*)d_in[6];   // f32 [64,64]

    const int K0 = in_sizes[2] / HID;   // 128
    const int N  = in_sizes[0] / K0;    // 100000
    const int E  = in_sizes[1] / 2;     // 1600000
    const int* srcp = ei;
    const int* dstp = ei + E;

    const int NH = N * HID;
    const size_t Npad = ((size_t)N + 255) & ~(size_t)255;

    float* ACC  = (float*)d_out;          // H buffer / final output f32 [N,64]
    float* dinv = (float*)d_ws;           // Npad
    float* tmp  = dinv + Npad;            // NH  (26MB total, proven region)

    // CSR scratch: degi(Npad) cursor(Npad) rp(Npad+256) bsum(1024) epay(2E ints)
    size_t csr_elems = 3 * Npad + 256 + 1024 + 2 * (size_t)E;
    int* csr_base;
    if (ws_size >= (Npad + (size_t)NH + csr_elems) * 4) {
        csr_base = (int*)(tmp + NH);
    } else {
        csr_base = (int*)d_in[0];         // x buffer, free after gemm_in
    }
    int*  degi   = csr_base;
    int*  cursor = degi + Npad;
    int*  rp     = cursor + Npad;
    int*  bsum   = rp + Npad + 256;
    int2* epay   = (int2*)(bsum + 1024);

    const int tgrid = (N + 63) / 64;
    const int agrid = (N + 3) / 4;
    const int nb    = (N + 1023) / 1024;

    // ---- layer-0 transform first (frees x for CSR scratch) ----
    gemm_tile<<<tgrid, 256, 0, stream>>>(x, W_in, tmp, N, 128);

    // ---- degree + norm ----
    zero_i<<<256, 256, 0, stream>>>(degi, (int)(2 * Npad));
    deg_i<<<2048, 256, 0, stream>>>(dstp, degi, E);
    dinv_k<<<(N + 255) / 256, 256, 0, stream>>>(degi, dinv, N);

    // ---- CSR build ----
    scan1<<<nb, 256, 0, stream>>>(degi, rp, bsum, N);
    scan2<<<1, 256, 0, stream>>>(bsum, nb);
    scan3<<<(N + 255) / 256, 256, 0, stream>>>(rp, bsum, N, N, E);
    scatter_k<<<2048, 256, 0, stream>>>(srcp, dstp, rp, cursor, dinv, epay, E);

    // ---- 5 GCN convs ----
    agg_csr<<<agrid, 256, 0, stream>>>(tmp, rp, epay, dinv, b_in, ACC, N, 0);
    for (int l = 0; l < 3; ++l) {
        gemm_tile<<<tgrid, 256, 0, stream>>>(ACC, W_h + (size_t)l * HID * HID, tmp, N, 64);
        agg_csr<<<agrid, 256, 0, stream>>>(tmp, rp, epay, dinv, b_h + (size_t)l * HID, ACC, N, 1);
    }
    gemm_tile<<<tgrid, 256, 0, stream>>>(ACC, W_out, tmp, N, 64);
    agg_csr<<<agrid, 256, 0, stream>>>(tmp, rp, epay, dinv, nullptr, ACC, N, 0);
}

// Round 11
// 682.125 us; speedup vs baseline: 3.3517x; 1.1452x over previous
//
#include <hip/hip_runtime.h>
#include <hip/hip_fp16.h>

#define HID 64

// R10: 781us; scatter_k top (81us, WRITE 102MB = 1.6M x 64B line evictions);
// agg ~70us/layer on f32 gathers (410MB/layer). R11:
//  - dinv[src] folded into tmp' at GEMM epilogue -> CSR payload = 4B src only,
//    agg inner loop = pure adds. out[d] = relu(di*(sum tmp'[s_j] + tmp'[d]) + b).
//  - tmp' stored fp16 (f32 accumulation): gather bytes halved, 12.8MB table.
//  - agg: lane-parallel esrc load + __shfl broadcast, 4-deep pipelined gathers.
//  - everything (20.8MB) in the proven d_ws region; x untouched.

__global__ void zero_i(int* __restrict__ p, int n) {
    int i = blockIdx.x * 256 + threadIdx.x, st = gridDim.x * 256;
    for (; i < n; i += st) p[i] = 0;
}

__global__ void deg_i(const int* __restrict__ dst, int* __restrict__ deg, int E) {
    int i = blockIdx.x * 256 + threadIdx.x, st = gridDim.x * 256;
    for (int e = i; e < E; e += st) atomicAdd(&deg[dst[e]], 1);
}

__global__ void dinv_k(const int* __restrict__ deg, float* __restrict__ dinv, int N) {
    int i = blockIdx.x * 256 + threadIdx.x;
    if (i < N) dinv[i] = rsqrtf((float)deg[i] + 1.0f);
}

// ---- scan stage 1: per-block (1024 elems) exclusive scan + block sums ----
__global__ void scan1(const int* __restrict__ in, int* __restrict__ out,
                      int* __restrict__ bsum, int n) {
    __shared__ int s[256];
    int t = threadIdx.x, base = blockIdx.x * 1024 + t * 4;
    int v0 = 0, v1 = 0, v2 = 0, v3 = 0;
    if (base + 0 < n) v0 = in[base + 0];
    if (base + 1 < n) v1 = in[base + 1];
    if (base + 2 < n) v2 = in[base + 2];
    if (base + 3 < n) v3 = in[base + 3];
    int sum = v0 + v1 + v2 + v3;
    s[t] = sum; __syncthreads();
    for (int off = 1; off < 256; off <<= 1) {
        int x = (t >= off) ? s[t - off] : 0;
        __syncthreads(); s[t] += x; __syncthreads();
    }
    if (t == 255) bsum[blockIdx.x] = s[255];
    int run = s[t] - sum;
    if (base + 0 < n) out[base + 0] = run; run += v0;
    if (base + 1 < n) out[base + 1] = run; run += v1;
    if (base + 2 < n) out[base + 2] = run; run += v2;
    if (base + 3 < n) out[base + 3] = run;
}

__global__ void scan2(int* __restrict__ bsum, int nb) {
    __shared__ int s[256];
    int t = threadIdx.x, base = t * 4;
    int v0 = 0, v1 = 0, v2 = 0, v3 = 0;
    if (base + 0 < nb) v0 = bsum[base + 0];
    if (base + 1 < nb) v1 = bsum[base + 1];
    if (base + 2 < nb) v2 = bsum[base + 2];
    if (base + 3 < nb) v3 = bsum[base + 3];
    int sum = v0 + v1 + v2 + v3;
    s[t] = sum; __syncthreads();
    for (int off = 1; off < 256; off <<= 1) {
        int x = (t >= off) ? s[t - off] : 0;
        __syncthreads(); s[t] += x; __syncthreads();
    }
    int run = s[t] - sum;
    if (base + 0 < nb) bsum[base + 0] = run; run += v0;
    if (base + 1 < nb) bsum[base + 1] = run; run += v1;
    if (base + 2 < nb) bsum[base + 2] = run; run += v2;
    if (base + 3 < nb) bsum[base + 3] = run;
}

__global__ void scan3(int* __restrict__ out, const int* __restrict__ bsum,
                      int n, int N, int E) {
    int i = blockIdx.x * 256 + threadIdx.x;
    if (i < n) out[i] += bsum[i >> 10];
    if (i == 0) out[N] = E;
}

// ---- scatter: esrc[pos] = src (4B payload; dinv folded into tmp') ----
__global__ void scatter_k(const int* __restrict__ src, const int* __restrict__ dst,
                          const int* __restrict__ rp, int* __restrict__ cursor,
                          int* __restrict__ esrc, int E) {
    int i = blockIdx.x * 256 + threadIdx.x, st = gridDim.x * 256;
    for (int e = i; e < E; e += st) {
        int s = src[e], d = dst[e];
        int pos = rp[d] + atomicAdd(&cursor[d], 1);
        esrc[pos] = s;
    }
}

// ---- register-tiled GEMM: tmp'[N,64](fp16) = (H[N,K] @ W[K,64]) * dinv[row] ----
// block = 256 thr, 64x64 tile; thread = 4 rows x 4 cols.
__global__ void gemm_tile(const float* __restrict__ H, const float* __restrict__ W,
                          const float* __restrict__ dinv, __half* __restrict__ out,
                          int N, int K) {
    __shared__ float h_s[64 * 65];   // [row][k], +1 pad
    __shared__ float w_s[64 * 64];   // [k][col]
    int tid  = threadIdx.x;
    int col4 = tid & 15;
    int rq   = (tid >> 4) & 3;
    int wv   = tid >> 6;
    int row0 = wv * 16 + rq * 4;
    int n0   = blockIdx.x * 64;
    float4 acc0 = {0,0,0,0}, acc1 = {0,0,0,0}, acc2 = {0,0,0,0}, acc3 = {0,0,0,0};
    int nchunk = K >> 6;
    for (int kc = 0; kc < nchunk; ++kc) {
        __syncthreads();
        for (int i = tid; i < 64 * 64; i += 256) {
            int r = i >> 6, k = i & 63;
            int nd = n0 + r;
            h_s[r * 65 + k] = (nd < N) ? H[(size_t)nd * K + kc * 64 + k] : 0.0f;
        }
        for (int i = tid; i < 64 * 64; i += 256) {
            int k = i >> 6, c = i & 63;
            w_s[i] = W[(size_t)(kc * 64 + k) * HID + c];
        }
        __syncthreads();
        #pragma unroll 8
        for (int k = 0; k < 64; ++k) {
            float4 w = *(const float4*)&w_s[k * 64 + col4 * 4];
            float h0 = h_s[(row0 + 0) * 65 + k];
            float h1 = h_s[(row0 + 1) * 65 + k];
            float h2 = h_s[(row0 + 2) * 65 + k];
            float h3 = h_s[(row0 + 3) * 65 + k];
            acc0.x = fmaf(h0, w.x, acc0.x); acc0.y = fmaf(h0, w.y, acc0.y);
            acc0.z = fmaf(h0, w.z, acc0.z); acc0.w = fmaf(h0, w.w, acc0.w);
            acc1.x = fmaf(h1, w.x, acc1.x); acc1.y = fmaf(h1, w.y, acc1.y);
            acc1.z = fmaf(h1, w.z, acc1.z); acc1.w = fmaf(h1, w.w, acc1.w);
            acc2.x = fmaf(h2, w.x, acc2.x); acc2.y = fmaf(h2, w.y, acc2.y);
            acc2.z = fmaf(h2, w.z, acc2.z); acc2.w = fmaf(h2, w.w, acc2.w);
            acc3.x = fmaf(h3, w.x, acc3.x); acc3.y = fmaf(h3, w.y, acc3.y);
            acc3.z = fmaf(h3, w.z, acc3.z); acc3.w = fmaf(h3, w.w, acc3.w);
        }
    }
    int nd0 = n0 + row0;
    #pragma unroll
    for (int r = 0; r < 4; ++r) {
        int nd = nd0 + r;
        if (nd < N) {
            float4 a = (r == 0) ? acc0 : (r == 1) ? acc1 : (r == 2) ? acc2 : acc3;
            float dv = dinv[nd];
            __half2* o = (__half2*)&out[(size_t)nd * HID + col4 * 4];
            o[0] = __halves2half2(__float2half_rn(a.x * dv), __float2half_rn(a.y * dv));
            o[1] = __halves2half2(__float2half_rn(a.z * dv), __float2half_rn(a.w * dv));
        }
    }
}

// ---- CSR aggregation, wave per dst node ----
// out[d] = relu?( dinv[d] * (tmp'[d] + sum_j tmp'[esrc_j]) + bias )
__global__ void agg_csr(const __half* __restrict__ tmp, const int* __restrict__ rp,
                        const int* __restrict__ esrc, const float* __restrict__ dinv,
                        const float* __restrict__ bias, float* __restrict__ out,
                        int N, int do_relu) {
    int d = blockIdx.x * 4 + (threadIdx.x >> 6);
    int lane = threadIdx.x & 63;                 // lane == column
    if (d >= N) return;
    float di = dinv[d];
    float accE = __half2float(tmp[(size_t)d * HID + lane]);   // self-loop term
    int j0 = rp[d], j1 = rp[d + 1];
    for (int base = j0; base < j1; base += 64) {
        int cnt = min(64, j1 - base);
        int sp = (lane < cnt) ? esrc[base + lane] : 0;   // coalesced 256B covers 64 edges
        int jj = 0;
        for (; jj + 3 < cnt; jj += 4) {                  // 4 gathers in flight
            int s0 = __shfl(sp, jj + 0);
            int s1 = __shfl(sp, jj + 1);
            int s2 = __shfl(sp, jj + 2);
            int s3 = __shfl(sp, jj + 3);
            float t0 = __half2float(tmp[(size_t)s0 * HID + lane]);
            float t1 = __half2float(tmp[(size_t)s1 * HID + lane]);
            float t2 = __half2float(tmp[(size_t)s2 * HID + lane]);
            float t3 = __half2float(tmp[(size_t)s3 * HID + lane]);
            accE += (t0 + t1) + (t2 + t3);
        }
        for (; jj < cnt; ++jj) {
            int s = __shfl(sp, jj);
            accE += __half2float(tmp[(size_t)s * HID + lane]);
        }
    }
    float v = di * accE;
    if (bias != nullptr) v += bias[lane];
    if (do_relu) v = fmaxf(v, 0.0f);
    out[(size_t)d * HID + lane] = v;
}

extern "C" void kernel_launch(void* const* d_in, const int* in_sizes, int n_in,
                              void* d_out, int out_size, void* d_ws, size_t ws_size,
                              hipStream_t stream) {
    const float* x     = (const float*)d_in[0];   // f32 [N,128]
    const int*   ei    = (const int*)d_in[1];     // int32 [2,E]
    const float* W_in  = (const float*)d_in[2];   // f32 [128,64]
    const float* b_in  = (const float*)d_in[3];   // f32 [64]
    const float* W_h   = (const float*)d_in[4];   // f32 [3,64,64]
    const float* b_h   = (const float*)d_in[5];   // f32 [3,64]
    const float* W_out = (const float*)d_in[6];   // f32 [64,64]

    const int K0 = in_sizes[2] / HID;   // 128
    const int N  = in_sizes[0] / K0;    // 100000
    const int E  = in_sizes[1] / 2;     // 1600000
    const int* srcp = ei;
    const int* dstp = ei + E;

    const int NH = N * HID;
    const size_t Npad = ((size_t)N + 255) & ~(size_t)255;

    float* ACC = (float*)d_out;                   // H buffer / final output f32 [N,64]

    // ws layout (total ~20.8MB, well inside the R8-proven 26MB region):
    float*  dinv = (float*)d_ws;                  // Npad f32          0.4 MB
    __half* tmp  = (__half*)(dinv + Npad);        // NH half          12.8 MB
    int*    degi   = (int*)(tmp + NH);            // Npad              0.4 MB
    int*    cursor = degi + Npad;                 // Npad              0.4 MB
    int*    rp     = cursor + Npad;               // Npad+256          0.4 MB
    int*    bsum   = rp + Npad + 256;             // 1024
    int*    esrc   = bsum + 1024;                 // E                 6.4 MB

    const int tgrid = (N + 63) / 64;
    const int agrid = (N + 3) / 4;
    const int nb    = (N + 1023) / 1024;

    // ---- degree + norm + CSR build (dinv-independent scatter) ----
    zero_i<<<256, 256, 0, stream>>>(degi, (int)(2 * Npad));     // degi + cursor
    deg_i<<<2048, 256, 0, stream>>>(dstp, degi, E);
    dinv_k<<<(N + 255) / 256, 256, 0, stream>>>(degi, dinv, N);
    scan1<<<nb, 256, 0, stream>>>(degi, rp, bsum, N);
    scan2<<<1, 256, 0, stream>>>(bsum, nb);
    scan3<<<(N + 255) / 256, 256, 0, stream>>>(rp, bsum, N, N, E);
    scatter_k<<<2048, 256, 0, stream>>>(srcp, dstp, rp, cursor, esrc, E);

    // ---- 5 GCN convs ----
    gemm_tile<<<tgrid, 256, 0, stream>>>(x, W_in, dinv, tmp, N, 128);
    agg_csr<<<agrid, 256, 0, stream>>>(tmp, rp, esrc, dinv, b_in, ACC, N, 0);
    for (int l = 0; l < 3; ++l) {
        gemm_tile<<<tgrid, 256, 0, stream>>>(ACC, W_h + (size_t)l * HID * HID, dinv, tmp, N, 64);
        agg_csr<<<agrid, 256, 0, stream>>>(tmp, rp, esrc, dinv, b_h + (size_t)l * HID, ACC, N, 1);
    }
    gemm_tile<<<tgrid, 256, 0, stream>>>(ACC, W_out, dinv, tmp, N, 64);
    agg_csr<<<agrid, 256, 0, stream>>>(tmp, rp, esrc, dinv, nullptr, ACC, N, 0);
}